// Round 9
// baseline (469.025 us; speedup 1.0000x reference)
//
#include <hip/hip_runtime.h>
#include <hip/hip_bf16.h>
#include <hip/hip_cooperative_groups.h>
#include <math.h>

namespace cg = cooperative_groups;

#define N_NODES 50000
#define N_EDGES 800000
// F_IN = HIDDEN = 128, N_CLASSES = 40; h2p rows padded to 48 (3 cache lines)

#define CSR_NB 256  // cooperative grid: 256 blocks x 256 threads (co-resident)

// ---------------- fused CSR build: zero + count + scan + fill, one dispatch --------
// Phases separated by grid.sync(). One thread per node for the scan (65536 >= 50001).
__global__ __launch_bounds__(256) void coop_csr_kernel(const int* __restrict__ ei,
                                                       int* __restrict__ cnt,
                                                       int* __restrict__ bsum,
                                                       int* __restrict__ rowptr,
                                                       int* __restrict__ cursor,
                                                       float* __restrict__ dinv,
                                                       int* __restrict__ col) {
  cg::grid_group grid = cg::this_grid();
  __shared__ int s[256];
  int t = threadIdx.x;
  int bid = blockIdx.x;
  int tid = bid * 256 + t;
  const int NT = CSR_NB * 256;  // 65536

  // phase 0: zero counters
  for (int i = tid; i < N_NODES; i += NT) cnt[i] = 0;
  grid.sync();

  // phase 1: in-degree histogram (indices clamped defensively)
  for (int e = tid; e < N_EDGES; e += NT) {
    int d = ei[N_EDGES + e];
    d = min(max(d, 0), N_NODES - 1);
    atomicAdd(&cnt[d], 1);
  }
  grid.sync();

  // phase 2a: block-local inclusive scan (one element per thread)
  int v = (tid < N_NODES) ? cnt[tid] : 0;
  s[t] = v;
  __syncthreads();
  for (int off = 1; off < 256; off <<= 1) {
    int a = (t >= off) ? s[t - off] : 0;
    __syncthreads();
    s[t] += a;
    __syncthreads();
  }
  int incl = s[t];
  int excl = incl - v;
  if (t == 255) bsum[bid] = incl;  // block total
  grid.sync();

  // phase 2b: block 0 scans the 256 block totals -> exclusive offsets
  if (bid == 0) {
    int b = bsum[t];
    s[t] = b;
    __syncthreads();
    for (int off = 1; off < 256; off <<= 1) {
      int a = (t >= off) ? s[t - off] : 0;
      __syncthreads();
      s[t] += a;
      __syncthreads();
    }
    bsum[t] = s[t] - b;  // exclusive
  }
  grid.sync();

  // phase 2c: write rowptr / cursor / dinv
  if (tid < N_NODES) {
    int e0 = excl + bsum[bid];
    rowptr[tid] = e0;
    cursor[tid] = e0;
    dinv[tid] = rsqrtf((float)(v + 1));  // deg includes self-loop, > 0
  }
  if (tid == 0) rowptr[N_NODES] = N_EDGES;
  grid.sync();

  // phase 3: fill column lists
  for (int e = tid; e < N_EDGES; e += NT) {
    int srcv = ei[e];
    int dstv = ei[N_EDGES + e];
    srcv = min(max(srcv, 0), N_NODES - 1);
    dstv = min(max(dstv, 0), N_NODES - 1);
    int p = atomicAdd(&cursor[dstv], 1);
    col[p] = srcv;
  }
}

// ---------------- GEMM1: h1p = dinv .* (X @ W1)  [50000x128 @ 128x128] ----------------
// 128x128 tile/block, BK=64 two-stage K loop -> 64 KiB LDS -> 2 blocks/CU.
__global__ __launch_bounds__(256) void gemm1_kernel(const float* __restrict__ X,
                                                    const float* __restrict__ W,
                                                    const float* __restrict__ dinv,
                                                    float* __restrict__ h1p) {
  __shared__ float xs[128 * 64];
  __shared__ float ws[128 * 64];
  int t = threadIdx.x;
  int row0 = blockIdx.x * 128;
  int wv = t >> 6, lane = t & 63;
  int wr = (wv >> 1) << 6, wc = (wv & 1) << 6;
  int tr = lane >> 3, tc = lane & 7;
  float acc[8][8];
#pragma unroll
  for (int i = 0; i < 8; ++i)
#pragma unroll
    for (int m = 0; m < 8; ++m) acc[i][m] = 0.f;

  for (int h = 0; h < 2; ++h) {
    if (h) __syncthreads();
#pragma unroll
    for (int it = 0; it < 8; ++it) {
      int idx = t + it * 256;
      int r = idx >> 4, kq = idx & 15;
      int gr = row0 + r;
      if (gr >= N_NODES) gr = N_NODES - 1;
      float4 v = *(const float4*)(X + (size_t)gr * 128 + h * 64 + kq * 4);
      *(float4*)(xs + r * 64 + ((kq ^ (r & 7)) << 2)) = v;
    }
#pragma unroll
    for (int it = 0; it < 8; ++it) {
      int idx = t + it * 256;
      int k = idx >> 5, jq = idx & 31;
      float4 v = *(const float4*)(W + (size_t)(h * 64 + k) * 128 + jq * 4);
      int kc = k >> 2, kr = k & 3;
      int j0 = jq * 4;
      ws[(j0 + 0) * 64 + (((kc ^ ((j0 + 0) & 7)) << 2) | kr)] = v.x;
      ws[(j0 + 1) * 64 + (((kc ^ ((j0 + 1) & 7)) << 2) | kr)] = v.y;
      ws[(j0 + 2) * 64 + (((kc ^ ((j0 + 2) & 7)) << 2) | kr)] = v.z;
      ws[(j0 + 3) * 64 + (((kc ^ ((j0 + 3) & 7)) << 2) | kr)] = v.w;
    }
    __syncthreads();
    for (int kq = 0; kq < 16; ++kq) {
      float4 xv[8], wvv[8];
#pragma unroll
      for (int i = 0; i < 8; ++i)
        xv[i] = *(const float4*)(xs + (wr + tr + 8 * i) * 64 + ((kq ^ tr) << 2));
#pragma unroll
      for (int m = 0; m < 8; ++m)
        wvv[m] = *(const float4*)(ws + (wc + tc + 8 * m) * 64 + ((kq ^ tc) << 2));
#pragma unroll
      for (int i = 0; i < 8; ++i)
#pragma unroll
        for (int m = 0; m < 8; ++m) {
          acc[i][m] = fmaf(xv[i].x, wvv[m].x, acc[i][m]);
          acc[i][m] = fmaf(xv[i].y, wvv[m].y, acc[i][m]);
          acc[i][m] = fmaf(xv[i].z, wvv[m].z, acc[i][m]);
          acc[i][m] = fmaf(xv[i].w, wvv[m].w, acc[i][m]);
        }
    }
  }
#pragma unroll
  for (int i = 0; i < 8; ++i) {
    int gr = row0 + wr + tr + 8 * i;
    if (gr < N_NODES) {
      float di = dinv[gr];
#pragma unroll
      for (int m = 0; m < 8; ++m)
        h1p[(size_t)gr * 128 + wc + tc + 8 * m] = di * acc[i][m];
    }
  }
}

// ---------------- layer-1 aggregation: x2 = relu(dinv.*(h1p + gather-sum) + b1) ------
// Half-wave per row (float4/lane), 4 independent accumulators. At the measured
// memory-system ceiling for random 512B gathers (~47% HBM + cache mix) — r7/r8
// identical timing across two structures.
__global__ __launch_bounds__(256) void agg1_kernel(const float* __restrict__ h1p,
                                                   const int* __restrict__ rowptr,
                                                   const int* __restrict__ col,
                                                   const float* __restrict__ dinv,
                                                   const float* __restrict__ b1,
                                                   float* __restrict__ x2) {
  int wid = (blockIdx.x * 256 + threadIdx.x) >> 6;  // one wave per node
  int lane = threadIdx.x & 63;
  if (wid >= N_NODES) return;
  int rs = rowptr[wid], re = rowptr[wid + 1];
  int half = lane >> 5;
  int fl = lane & 31;
  const float4* hp4 = (const float4*)h1p;
  float4 z = {0.f, 0.f, 0.f, 0.f};
  float4 a0 = (half == 0) ? hp4[(size_t)wid * 32 + fl] : z;  // self-loop
  float4 a1 = z, a2 = z, a3 = z;
  for (int base = rs; base < re; base += 64) {
    int idx = base + lane;
    int c = (idx < re) ? col[idx] : 0;
    int nb = min(64, re - base);
    int e = 0;
    for (; e + 8 <= nb; e += 8) {
      int s0 = __shfl(c, e + half);
      int s1 = __shfl(c, e + 2 + half);
      int s2 = __shfl(c, e + 4 + half);
      int s3 = __shfl(c, e + 6 + half);
      float4 v0 = hp4[(size_t)s0 * 32 + fl];
      float4 v1 = hp4[(size_t)s1 * 32 + fl];
      float4 v2 = hp4[(size_t)s2 * 32 + fl];
      float4 v3 = hp4[(size_t)s3 * 32 + fl];
      a0.x += v0.x; a0.y += v0.y; a0.z += v0.z; a0.w += v0.w;
      a1.x += v1.x; a1.y += v1.y; a1.z += v1.z; a1.w += v1.w;
      a2.x += v2.x; a2.y += v2.y; a2.z += v2.z; a2.w += v2.w;
      a3.x += v3.x; a3.y += v3.y; a3.z += v3.z; a3.w += v3.w;
    }
    for (; e + 2 <= nb; e += 2) {
      int s0 = __shfl(c, e + half);
      float4 v0 = hp4[(size_t)s0 * 32 + fl];
      a0.x += v0.x; a0.y += v0.y; a0.z += v0.z; a0.w += v0.w;
    }
    if (e < nb) {
      int s0 = __shfl(c, e);
      if (half == 0) {
        float4 v0 = hp4[(size_t)s0 * 32 + fl];
        a0.x += v0.x; a0.y += v0.y; a0.z += v0.z; a0.w += v0.w;
      }
    }
  }
  float4 a;
  a.x = (a0.x + a1.x) + (a2.x + a3.x);
  a.y = (a0.y + a1.y) + (a2.y + a3.y);
  a.z = (a0.z + a1.z) + (a2.z + a3.z);
  a.w = (a0.w + a1.w) + (a2.w + a3.w);
  a.x += __shfl_xor(a.x, 32);
  a.y += __shfl_xor(a.y, 32);
  a.z += __shfl_xor(a.z, 32);
  a.w += __shfl_xor(a.w, 32);
  if (half == 0) {
    float di = dinv[wid];
    float4 bb = ((const float4*)b1)[fl];
    float4 o;
    o.x = fmaxf(fmaf(di, a.x, bb.x), 0.f);
    o.y = fmaxf(fmaf(di, a.y, bb.y), 0.f);
    o.z = fmaxf(fmaf(di, a.z, bb.z), 0.f);
    o.w = fmaxf(fmaf(di, a.w, bb.w), 0.f);
    *(float4*)(x2 + (size_t)wid * 128 + fl * 4) = o;
  }
}

// ---------------- GEMM2: h2p = dinv .* (x2 @ W2), rows PADDED to 48 floats ----------
__global__ __launch_bounds__(256) void gemm2_kernel(const float* __restrict__ X2,
                                                    const float* __restrict__ W2,
                                                    const float* __restrict__ dinv,
                                                    float* __restrict__ h2p) {
  __shared__ float xs[64 * 128];
  __shared__ float ws[40 * 128];
  int t = threadIdx.x;
  int row0 = blockIdx.x * 64;
#pragma unroll
  for (int it = 0; it < 8; ++it) {
    int idx = t + it * 256;
    int r = idx >> 5, kq = idx & 31;
    int gr = row0 + r;
    if (gr >= N_NODES) gr = N_NODES - 1;
    float4 v = *(const float4*)(X2 + (size_t)gr * 128 + kq * 4);
    *(float4*)(xs + r * 128 + ((kq ^ (r & 7)) << 2)) = v;
  }
  for (int idx = t; idx < 1280; idx += 256) {  // W2: [128][40] -> ws[j][swz(k)]
    int k = idx / 10, jq = idx % 10;
    float4 v = *(const float4*)(W2 + k * 40 + jq * 4);
    int kc = k >> 2, kr = k & 3;
    int j0 = jq * 4;
    ws[(j0 + 0) * 128 + (((kc ^ ((j0 + 0) & 7)) << 2) | kr)] = v.x;
    ws[(j0 + 1) * 128 + (((kc ^ ((j0 + 1) & 7)) << 2) | kr)] = v.y;
    ws[(j0 + 2) * 128 + (((kc ^ ((j0 + 2) & 7)) << 2) | kr)] = v.z;
    ws[(j0 + 3) * 128 + (((kc ^ ((j0 + 3) & 7)) << 2) | kr)] = v.w;
  }
  __syncthreads();
  int wv = t >> 6, lane = t & 63;
  int tr = lane >> 3, tc = lane & 7;
  int rbase = wv * 16;
  float acc[2][5];
#pragma unroll
  for (int i = 0; i < 2; ++i)
#pragma unroll
    for (int m = 0; m < 5; ++m) acc[i][m] = 0.f;
  for (int kq = 0; kq < 32; ++kq) {
    float4 xv[2], wvv[5];
#pragma unroll
    for (int i = 0; i < 2; ++i)
      xv[i] = *(const float4*)(xs + (rbase + tr + 8 * i) * 128 + ((kq ^ tr) << 2));
#pragma unroll
    for (int m = 0; m < 5; ++m)
      wvv[m] = *(const float4*)(ws + (tc + 8 * m) * 128 + ((kq ^ tc) << 2));
#pragma unroll
    for (int i = 0; i < 2; ++i)
#pragma unroll
      for (int m = 0; m < 5; ++m) {
        acc[i][m] = fmaf(xv[i].x, wvv[m].x, acc[i][m]);
        acc[i][m] = fmaf(xv[i].y, wvv[m].y, acc[i][m]);
        acc[i][m] = fmaf(xv[i].z, wvv[m].z, acc[i][m]);
        acc[i][m] = fmaf(xv[i].w, wvv[m].w, acc[i][m]);
      }
  }
#pragma unroll
  for (int i = 0; i < 2; ++i) {
    int gr = row0 + rbase + tr + 8 * i;
    if (gr < N_NODES) {
      float di = dinv[gr];
#pragma unroll
      for (int m = 0; m < 5; ++m)
        h2p[(size_t)gr * 48 + tc + 8 * m] = di * acc[i][m];  // padded stride
    }
  }
}

// ------- layer-2 aggregation fused with bias + log_softmax, writes d_out -------
__global__ __launch_bounds__(256) void agg2_softmax_kernel(const float* __restrict__ h2p,
                                                           const int* __restrict__ rowptr,
                                                           const int* __restrict__ col,
                                                           const float* __restrict__ dinv,
                                                           const float* __restrict__ b2,
                                                           float* __restrict__ out) {
  int wid = (blockIdx.x * 256 + threadIdx.x) >> 6;  // one wave per node
  int lane = threadIdx.x & 63;
  if (wid >= N_NODES) return;
  int rs = rowptr[wid], re = rowptr[wid + 1];
  bool act = lane < 40;
  float ac0 = act ? h2p[(size_t)wid * 48 + lane] : 0.f;
  float ac1 = 0.f, ac2 = 0.f, ac3 = 0.f;
  for (int base = rs; base < re; base += 64) {
    int idx = base + lane;
    int c = (idx < re) ? col[idx] : 0;
    int nb = min(64, re - base);
    int e = 0;
    for (; e + 4 <= nb; e += 4) {
      int s0 = __shfl(c, e), s1 = __shfl(c, e + 1);
      int s2 = __shfl(c, e + 2), s3 = __shfl(c, e + 3);
      if (act) {
        ac0 += h2p[(size_t)s0 * 48 + lane];
        ac1 += h2p[(size_t)s1 * 48 + lane];
        ac2 += h2p[(size_t)s2 * 48 + lane];
        ac3 += h2p[(size_t)s3 * 48 + lane];
      }
    }
    for (; e < nb; ++e) {
      int s0 = __shfl(c, e);
      if (act) ac0 += h2p[(size_t)s0 * 48 + lane];
    }
  }
  float acc = (ac0 + ac1) + (ac2 + ac3);
  float v = act ? fmaf(dinv[wid], acc, b2[lane]) : -1e30f;
  float m = v;
#pragma unroll
  for (int off = 32; off > 0; off >>= 1) m = fmaxf(m, __shfl_xor(m, off));
  float ex = act ? expf(v - m) : 0.f;
  float ssum = ex;
#pragma unroll
  for (int off = 32; off > 0; off >>= 1) ssum += __shfl_xor(ssum, off);
  float ls = logf(ssum);
  if (act) out[(size_t)wid * 40 + lane] = v - m - ls;
}

extern "C" void kernel_launch(void* const* d_in, const int* in_sizes, int n_in,
                              void* d_out, int out_size, void* d_ws, size_t ws_size,
                              hipStream_t stream) {
  const float* X = (const float*)d_in[0];
  const int* ei = (const int*)d_in[1];  // [2][E] int32 per harness contract
  const float* W1 = (const float*)d_in[2];
  const float* b1 = (const float*)d_in[3];
  const float* W2 = (const float*)d_in[4];
  const float* b2 = (const float*)d_in[5];
  float* out = (float*)d_out;

  char* p = (char*)d_ws;
  auto carve = [&](size_t bytes) -> void* {
    void* q = (void*)p;
    p += (bytes + 255) & ~(size_t)255;
    return q;
  };
  float* h1p = (float*)carve((size_t)N_NODES * 128 * 4);  // 25.6 MB
  float* x2 = (float*)carve((size_t)N_NODES * 128 * 4);   // 25.6 MB
  float* h2p = (float*)carve((size_t)N_NODES * 48 * 4);   // 9.6 MB (padded rows)
  int* col = (int*)carve((size_t)N_EDGES * 4);            // 3.2 MB
  int* cnt = (int*)carve((size_t)N_NODES * 4);
  int* rowptr = (int*)carve((size_t)(N_NODES + 1) * 4);
  int* cursor = (int*)carve((size_t)N_NODES * 4);
  float* dinv = (float*)carve((size_t)N_NODES * 4);
  int* bsum = (int*)carve((size_t)CSR_NB * 4);

  void* csr_args[] = {(void*)&ei, (void*)&cnt, (void*)&bsum, (void*)&rowptr,
                      (void*)&cursor, (void*)&dinv, (void*)&col};
  hipLaunchCooperativeKernel((const void*)coop_csr_kernel, dim3(CSR_NB), dim3(256),
                             csr_args, 0, stream);
  gemm1_kernel<<<(N_NODES + 127) / 128, 256, 0, stream>>>(X, W1, dinv, h1p);
  agg1_kernel<<<(N_NODES + 3) / 4, 256, 0, stream>>>(h1p, rowptr, col, dinv, b1, x2);
  gemm2_kernel<<<(N_NODES + 63) / 64, 256, 0, stream>>>(x2, W2, dinv, h2p);
  agg2_softmax_kernel<<<(N_NODES + 3) / 4, 256, 0, stream>>>(h2p, rowptr, col, dinv, b2, out);
}

// Round 10
// 462.158 us; speedup vs baseline: 1.0149x; 1.0149x over previous
//
#include <hip/hip_runtime.h>
#include <hip/hip_bf16.h>
#include <math.h>

#define N_NODES 50000
#define N_EDGES 800000
// F_IN = HIDDEN = 128, N_CLASSES = 40; h2p rows padded to 48 floats (3 cache lines)

// ---------------- degree histogram ----------------
__global__ __launch_bounds__(256) void count_kernel(const int* __restrict__ ei,
                                                    int* __restrict__ cnt) {
  int e = blockIdx.x * 256 + threadIdx.x;
  if (e < N_EDGES) {
    int d = ei[N_EDGES + e];
    d = min(max(d, 0), N_NODES - 1);  // defensive clamp
    atomicAdd(&cnt[d], 1);
  }
}

// ---------------- single-dispatch exclusive scan (replaces 3 scan kernels) ---------
// One block, 1024 threads, 49 elements/thread: per-thread sum -> block scan -> emit.
__global__ __launch_bounds__(1024) void scan_one_kernel(const int* __restrict__ cnt,
                                                        int* __restrict__ rowptr,
                                                        int* __restrict__ cursor,
                                                        float* __restrict__ dinv) {
  __shared__ int s[1024];
  int t = threadIdx.x;
  const int CH = (N_NODES + 1023) / 1024;  // 49
  int i0 = t * CH;
  int sum = 0;
  for (int j = 0; j < CH; ++j) {
    int i = i0 + j;
    if (i < N_NODES) sum += cnt[i];
  }
  s[t] = sum;
  __syncthreads();
  for (int off = 1; off < 1024; off <<= 1) {
    int a = (t >= off) ? s[t - off] : 0;
    __syncthreads();
    s[t] += a;
    __syncthreads();
  }
  int run = s[t] - sum;  // exclusive prefix of this thread's chunk
  for (int j = 0; j < CH; ++j) {
    int i = i0 + j;
    if (i < N_NODES) {
      int c = cnt[i];  // L2 hit (just read in pass 1)
      rowptr[i] = run;
      cursor[i] = run;
      dinv[i] = rsqrtf((float)(c + 1));  // deg includes self-loop, > 0
      run += c;
    }
  }
  if (t == 0) rowptr[N_NODES] = N_EDGES;
}

__global__ __launch_bounds__(256) void fill_kernel(const int* __restrict__ ei,
                                                   int* __restrict__ cursor,
                                                   int* __restrict__ col) {
  int e = blockIdx.x * 256 + threadIdx.x;
  if (e >= N_EDGES) return;
  int srcv = ei[e];
  int dstv = ei[N_EDGES + e];
  srcv = min(max(srcv, 0), N_NODES - 1);
  dstv = min(max(dstv, 0), N_NODES - 1);
  int p = atomicAdd(&cursor[dstv], 1);
  col[p] = srcv;
}

// ---------------- GEMM1: h1p = dinv .* (X @ W1)  [50000x128 @ 128x128] ----------------
// 128x128 tile/block, BK=64 two-stage K loop -> 64 KiB LDS -> 2 blocks/CU.
__global__ __launch_bounds__(256) void gemm1_kernel(const float* __restrict__ X,
                                                    const float* __restrict__ W,
                                                    const float* __restrict__ dinv,
                                                    float* __restrict__ h1p) {
  __shared__ float xs[128 * 64];
  __shared__ float ws[128 * 64];
  int t = threadIdx.x;
  int row0 = blockIdx.x * 128;
  int wv = t >> 6, lane = t & 63;
  int wr = (wv >> 1) << 6, wc = (wv & 1) << 6;
  int tr = lane >> 3, tc = lane & 7;
  float acc[8][8];
#pragma unroll
  for (int i = 0; i < 8; ++i)
#pragma unroll
    for (int m = 0; m < 8; ++m) acc[i][m] = 0.f;

  for (int h = 0; h < 2; ++h) {
    if (h) __syncthreads();
#pragma unroll
    for (int it = 0; it < 8; ++it) {
      int idx = t + it * 256;
      int r = idx >> 4, kq = idx & 15;
      int gr = row0 + r;
      if (gr >= N_NODES) gr = N_NODES - 1;
      float4 v = *(const float4*)(X + (size_t)gr * 128 + h * 64 + kq * 4);
      *(float4*)(xs + r * 64 + ((kq ^ (r & 7)) << 2)) = v;
    }
#pragma unroll
    for (int it = 0; it < 8; ++it) {
      int idx = t + it * 256;
      int k = idx >> 5, jq = idx & 31;
      float4 v = *(const float4*)(W + (size_t)(h * 64 + k) * 128 + jq * 4);
      int kc = k >> 2, kr = k & 3;
      int j0 = jq * 4;
      ws[(j0 + 0) * 64 + (((kc ^ ((j0 + 0) & 7)) << 2) | kr)] = v.x;
      ws[(j0 + 1) * 64 + (((kc ^ ((j0 + 1) & 7)) << 2) | kr)] = v.y;
      ws[(j0 + 2) * 64 + (((kc ^ ((j0 + 2) & 7)) << 2) | kr)] = v.z;
      ws[(j0 + 3) * 64 + (((kc ^ ((j0 + 3) & 7)) << 2) | kr)] = v.w;
    }
    __syncthreads();
    for (int kq = 0; kq < 16; ++kq) {
      float4 xv[8], wvv[8];
#pragma unroll
      for (int i = 0; i < 8; ++i)
        xv[i] = *(const float4*)(xs + (wr + tr + 8 * i) * 64 + ((kq ^ tr) << 2));
#pragma unroll
      for (int m = 0; m < 8; ++m)
        wvv[m] = *(const float4*)(ws + (wc + tc + 8 * m) * 64 + ((kq ^ tc) << 2));
#pragma unroll
      for (int i = 0; i < 8; ++i)
#pragma unroll
        for (int m = 0; m < 8; ++m) {
          acc[i][m] = fmaf(xv[i].x, wvv[m].x, acc[i][m]);
          acc[i][m] = fmaf(xv[i].y, wvv[m].y, acc[i][m]);
          acc[i][m] = fmaf(xv[i].z, wvv[m].z, acc[i][m]);
          acc[i][m] = fmaf(xv[i].w, wvv[m].w, acc[i][m]);
        }
    }
  }
#pragma unroll
  for (int i = 0; i < 8; ++i) {
    int gr = row0 + wr + tr + 8 * i;
    if (gr < N_NODES) {
      float di = dinv[gr];
#pragma unroll
      for (int m = 0; m < 8; ++m)
        h1p[(size_t)gr * 128 + wc + tc + 8 * m] = di * acc[i][m];
    }
  }
}

// ---------------- layer-1 aggregation: x2 = relu(dinv.*(h1p + gather-sum) + b1) ------
// Half-wave per row (float4/lane), 4 independent accumulators. At the measured
// memory-system ceiling (~3.75 TB/s L2-miss service) — r7/r8 identical across
// two different structures.
__global__ __launch_bounds__(256) void agg1_kernel(const float* __restrict__ h1p,
                                                   const int* __restrict__ rowptr,
                                                   const int* __restrict__ col,
                                                   const float* __restrict__ dinv,
                                                   const float* __restrict__ b1,
                                                   float* __restrict__ x2) {
  int wid = (blockIdx.x * 256 + threadIdx.x) >> 6;  // one wave per node
  int lane = threadIdx.x & 63;
  if (wid >= N_NODES) return;
  int rs = rowptr[wid], re = rowptr[wid + 1];
  int half = lane >> 5;
  int fl = lane & 31;
  const float4* hp4 = (const float4*)h1p;
  float4 z = {0.f, 0.f, 0.f, 0.f};
  float4 a0 = (half == 0) ? hp4[(size_t)wid * 32 + fl] : z;  // self-loop
  float4 a1 = z, a2 = z, a3 = z;
  for (int base = rs; base < re; base += 64) {
    int idx = base + lane;
    int c = (idx < re) ? col[idx] : 0;
    int nb = min(64, re - base);
    int e = 0;
    for (; e + 8 <= nb; e += 8) {
      int s0 = __shfl(c, e + half);
      int s1 = __shfl(c, e + 2 + half);
      int s2 = __shfl(c, e + 4 + half);
      int s3 = __shfl(c, e + 6 + half);
      float4 v0 = hp4[(size_t)s0 * 32 + fl];
      float4 v1 = hp4[(size_t)s1 * 32 + fl];
      float4 v2 = hp4[(size_t)s2 * 32 + fl];
      float4 v3 = hp4[(size_t)s3 * 32 + fl];
      a0.x += v0.x; a0.y += v0.y; a0.z += v0.z; a0.w += v0.w;
      a1.x += v1.x; a1.y += v1.y; a1.z += v1.z; a1.w += v1.w;
      a2.x += v2.x; a2.y += v2.y; a2.z += v2.z; a2.w += v2.w;
      a3.x += v3.x; a3.y += v3.y; a3.z += v3.z; a3.w += v3.w;
    }
    for (; e + 2 <= nb; e += 2) {
      int s0 = __shfl(c, e + half);
      float4 v0 = hp4[(size_t)s0 * 32 + fl];
      a0.x += v0.x; a0.y += v0.y; a0.z += v0.z; a0.w += v0.w;
    }
    if (e < nb) {
      int s0 = __shfl(c, e);
      if (half == 0) {
        float4 v0 = hp4[(size_t)s0 * 32 + fl];
        a0.x += v0.x; a0.y += v0.y; a0.z += v0.z; a0.w += v0.w;
      }
    }
  }
  float4 a;
  a.x = (a0.x + a1.x) + (a2.x + a3.x);
  a.y = (a0.y + a1.y) + (a2.y + a3.y);
  a.z = (a0.z + a1.z) + (a2.z + a3.z);
  a.w = (a0.w + a1.w) + (a2.w + a3.w);
  a.x += __shfl_xor(a.x, 32);
  a.y += __shfl_xor(a.y, 32);
  a.z += __shfl_xor(a.z, 32);
  a.w += __shfl_xor(a.w, 32);
  if (half == 0) {
    float di = dinv[wid];
    float4 bb = ((const float4*)b1)[fl];
    float4 o;
    o.x = fmaxf(fmaf(di, a.x, bb.x), 0.f);
    o.y = fmaxf(fmaf(di, a.y, bb.y), 0.f);
    o.z = fmaxf(fmaf(di, a.z, bb.z), 0.f);
    o.w = fmaxf(fmaf(di, a.w, bb.w), 0.f);
    *(float4*)(x2 + (size_t)wid * 128 + fl * 4) = o;
  }
}

// ---------------- GEMM2: h2p = dinv .* (x2 @ W2), rows PADDED to 48 floats ----------
__global__ __launch_bounds__(256) void gemm2_kernel(const float* __restrict__ X2,
                                                    const float* __restrict__ W2,
                                                    const float* __restrict__ dinv,
                                                    float* __restrict__ h2p) {
  __shared__ float xs[64 * 128];
  __shared__ float ws[40 * 128];
  int t = threadIdx.x;
  int row0 = blockIdx.x * 64;
#pragma unroll
  for (int it = 0; it < 8; ++it) {
    int idx = t + it * 256;
    int r = idx >> 5, kq = idx & 31;
    int gr = row0 + r;
    if (gr >= N_NODES) gr = N_NODES - 1;
    float4 v = *(const float4*)(X2 + (size_t)gr * 128 + kq * 4);
    *(float4*)(xs + r * 128 + ((kq ^ (r & 7)) << 2)) = v;
  }
  for (int idx = t; idx < 1280; idx += 256) {  // W2: [128][40] -> ws[j][swz(k)]
    int k = idx / 10, jq = idx % 10;
    float4 v = *(const float4*)(W2 + k * 40 + jq * 4);
    int kc = k >> 2, kr = k & 3;
    int j0 = jq * 4;
    ws[(j0 + 0) * 128 + (((kc ^ ((j0 + 0) & 7)) << 2) | kr)] = v.x;
    ws[(j0 + 1) * 128 + (((kc ^ ((j0 + 1) & 7)) << 2) | kr)] = v.y;
    ws[(j0 + 2) * 128 + (((kc ^ ((j0 + 2) & 7)) << 2) | kr)] = v.z;
    ws[(j0 + 3) * 128 + (((kc ^ ((j0 + 3) & 7)) << 2) | kr)] = v.w;
  }
  __syncthreads();
  int wv = t >> 6, lane = t & 63;
  int tr = lane >> 3, tc = lane & 7;
  int rbase = wv * 16;
  float acc[2][5];
#pragma unroll
  for (int i = 0; i < 2; ++i)
#pragma unroll
    for (int m = 0; m < 5; ++m) acc[i][m] = 0.f;
  for (int kq = 0; kq < 32; ++kq) {
    float4 xv[2], wvv[5];
#pragma unroll
    for (int i = 0; i < 2; ++i)
      xv[i] = *(const float4*)(xs + (rbase + tr + 8 * i) * 128 + ((kq ^ tr) << 2));
#pragma unroll
    for (int m = 0; m < 5; ++m)
      wvv[m] = *(const float4*)(ws + (tc + 8 * m) * 128 + ((kq ^ tc) << 2));
#pragma unroll
    for (int i = 0; i < 2; ++i)
#pragma unroll
      for (int m = 0; m < 5; ++m) {
        acc[i][m] = fmaf(xv[i].x, wvv[m].x, acc[i][m]);
        acc[i][m] = fmaf(xv[i].y, wvv[m].y, acc[i][m]);
        acc[i][m] = fmaf(xv[i].z, wvv[m].z, acc[i][m]);
        acc[i][m] = fmaf(xv[i].w, wvv[m].w, acc[i][m]);
      }
  }
#pragma unroll
  for (int i = 0; i < 2; ++i) {
    int gr = row0 + rbase + tr + 8 * i;
    if (gr < N_NODES) {
      float di = dinv[gr];
#pragma unroll
      for (int m = 0; m < 5; ++m)
        h2p[(size_t)gr * 48 + tc + 8 * m] = di * acc[i][m];  // padded stride
    }
  }
}

// ------- layer-2 aggregation fused with bias + log_softmax, writes d_out -------
__global__ __launch_bounds__(256) void agg2_softmax_kernel(const float* __restrict__ h2p,
                                                           const int* __restrict__ rowptr,
                                                           const int* __restrict__ col,
                                                           const float* __restrict__ dinv,
                                                           const float* __restrict__ b2,
                                                           float* __restrict__ out) {
  int wid = (blockIdx.x * 256 + threadIdx.x) >> 6;  // one wave per node
  int lane = threadIdx.x & 63;
  if (wid >= N_NODES) return;
  int rs = rowptr[wid], re = rowptr[wid + 1];
  bool act = lane < 40;
  float ac0 = act ? h2p[(size_t)wid * 48 + lane] : 0.f;
  float ac1 = 0.f, ac2 = 0.f, ac3 = 0.f;
  for (int base = rs; base < re; base += 64) {
    int idx = base + lane;
    int c = (idx < re) ? col[idx] : 0;
    int nb = min(64, re - base);
    int e = 0;
    for (; e + 4 <= nb; e += 4) {
      int s0 = __shfl(c, e), s1 = __shfl(c, e + 1);
      int s2 = __shfl(c, e + 2), s3 = __shfl(c, e + 3);
      if (act) {
        ac0 += h2p[(size_t)s0 * 48 + lane];
        ac1 += h2p[(size_t)s1 * 48 + lane];
        ac2 += h2p[(size_t)s2 * 48 + lane];
        ac3 += h2p[(size_t)s3 * 48 + lane];
      }
    }
    for (; e < nb; ++e) {
      int s0 = __shfl(c, e);
      if (act) ac0 += h2p[(size_t)s0 * 48 + lane];
    }
  }
  float acc = (ac0 + ac1) + (ac2 + ac3);
  float v = act ? fmaf(dinv[wid], acc, b2[lane]) : -1e30f;
  float m = v;
#pragma unroll
  for (int off = 32; off > 0; off >>= 1) m = fmaxf(m, __shfl_xor(m, off));
  float ex = act ? expf(v - m) : 0.f;
  float ssum = ex;
#pragma unroll
  for (int off = 32; off > 0; off >>= 1) ssum += __shfl_xor(ssum, off);
  float ls = logf(ssum);
  if (act) out[(size_t)wid * 40 + lane] = v - m - ls;
}

extern "C" void kernel_launch(void* const* d_in, const int* in_sizes, int n_in,
                              void* d_out, int out_size, void* d_ws, size_t ws_size,
                              hipStream_t stream) {
  const float* X = (const float*)d_in[0];
  const int* ei = (const int*)d_in[1];  // [2][E] int32 per harness contract
  const float* W1 = (const float*)d_in[2];
  const float* b1 = (const float*)d_in[3];
  const float* W2 = (const float*)d_in[4];
  const float* b2 = (const float*)d_in[5];
  float* out = (float*)d_out;

  char* p = (char*)d_ws;
  auto carve = [&](size_t bytes) -> void* {
    void* q = (void*)p;
    p += (bytes + 255) & ~(size_t)255;
    return q;
  };
  float* h1p = (float*)carve((size_t)N_NODES * 128 * 4);  // 25.6 MB
  float* x2 = (float*)carve((size_t)N_NODES * 128 * 4);   // 25.6 MB
  float* h2p = (float*)carve((size_t)N_NODES * 48 * 4);   // 9.6 MB (padded rows)
  int* col = (int*)carve((size_t)N_EDGES * 4);            // 3.2 MB
  int* cnt = (int*)carve((size_t)N_NODES * 4);
  int* rowptr = (int*)carve((size_t)(N_NODES + 1) * 4);
  int* cursor = (int*)carve((size_t)N_NODES * 4);
  float* dinv = (float*)carve((size_t)N_NODES * 4);

  hipMemsetAsync(cnt, 0, (size_t)N_NODES * 4, stream);
  count_kernel<<<(N_EDGES + 255) / 256, 256, 0, stream>>>(ei, cnt);
  scan_one_kernel<<<1, 1024, 0, stream>>>(cnt, rowptr, cursor, dinv);
  fill_kernel<<<(N_EDGES + 255) / 256, 256, 0, stream>>>(ei, cursor, col);
  gemm1_kernel<<<(N_NODES + 127) / 128, 256, 0, stream>>>(X, W1, dinv, h1p);
  agg1_kernel<<<(N_NODES + 3) / 4, 256, 0, stream>>>(h1p, rowptr, col, dinv, b1, x2);
  gemm2_kernel<<<(N_NODES + 63) / 64, 256, 0, stream>>>(x2, W2, dinv, h2p);
  agg2_softmax_kernel<<<(N_NODES + 3) / 4, 256, 0, stream>>>(h2p, rowptr, col, dinv, b2, out);
}

// Round 12
// 296.184 us; speedup vs baseline: 1.5836x; 1.5604x over previous
//
#include <hip/hip_runtime.h>
#include <hip/hip_bf16.h>
#include <math.h>

#define N_NODES 50000
#define N_EDGES 800000
// F_IN = HIDDEN = 128, N_CLASSES = 40
// h1p: bf16, row stride 128 (256 B). h2p: f32, rows padded to 48 (3 cache lines).

#define SCAN_CHUNK 512
#define SCAN_NB ((N_NODES + SCAN_CHUNK - 1) / SCAN_CHUNK)  // 98

// ---------------- degree histogram ----------------
__global__ __launch_bounds__(256) void count_kernel(const int* __restrict__ ei,
                                                    int* __restrict__ cnt) {
  int e = blockIdx.x * 256 + threadIdx.x;
  if (e < N_EDGES) {
    int d = ei[N_EDGES + e];
    d = min(max(d, 0), N_NODES - 1);  // defensive clamp
    atomicAdd(&cnt[d], 1);
  }
}

// ---------------- 3-pass exclusive scan (R8 known-good; coop/single-block fusions
// both regressed: 256-block coop grid = 220us, 1-block scan = 148us. occupancy!) ----
__global__ __launch_bounds__(256) void scan_reduce(const int* __restrict__ cnt,
                                                   int* __restrict__ bsum) {
  __shared__ int s[256];
  int t = threadIdx.x;
  int i0 = blockIdx.x * SCAN_CHUNK + t * 2;
  int v = 0;
  if (i0 < N_NODES) v += cnt[i0];
  if (i0 + 1 < N_NODES) v += cnt[i0 + 1];
  s[t] = v;
  __syncthreads();
  for (int off = 128; off > 0; off >>= 1) {
    if (t < off) s[t] += s[t + off];
    __syncthreads();
  }
  if (t == 0) bsum[blockIdx.x] = s[0];
}

__global__ void scan_block(int* bsum) {
  __shared__ int s[128];
  int t = threadIdx.x;
  int v = (t < SCAN_NB) ? bsum[t] : 0;
  s[t] = v;
  __syncthreads();
  for (int off = 1; off < 128; off <<= 1) {
    int a = (t >= off) ? s[t - off] : 0;
    __syncthreads();
    s[t] += a;
    __syncthreads();
  }
  if (t < SCAN_NB) bsum[t] = s[t] - v;  // exclusive
}

__global__ __launch_bounds__(256) void scan_final(const int* __restrict__ cnt,
                                                  const int* __restrict__ bsum,
                                                  int* __restrict__ rowptr,
                                                  int* __restrict__ cursor,
                                                  float* __restrict__ dinv) {
  __shared__ int s[256];
  int t = threadIdx.x;
  int b = blockIdx.x;
  int i0 = b * SCAN_CHUNK + t * 2;
  int c0 = (i0 < N_NODES) ? cnt[i0] : 0;
  int c1 = (i0 + 1 < N_NODES) ? cnt[i0 + 1] : 0;
  int v = c0 + c1;
  s[t] = v;
  __syncthreads();
  for (int off = 1; off < 256; off <<= 1) {
    int a = (t >= off) ? s[t - off] : 0;
    __syncthreads();
    s[t] += a;
    __syncthreads();
  }
  int excl = s[t] - v + bsum[b];
  if (i0 < N_NODES) {
    rowptr[i0] = excl;
    cursor[i0] = excl;
    dinv[i0] = rsqrtf((float)(c0 + 1));  // deg includes self-loop, > 0
  }
  if (i0 + 1 < N_NODES) {
    rowptr[i0 + 1] = excl + c0;
    cursor[i0 + 1] = excl + c0;
    dinv[i0 + 1] = rsqrtf((float)(c1 + 1));
  }
  if (b == 0 && t == 0) rowptr[N_NODES] = N_EDGES;
}

__global__ __launch_bounds__(256) void fill_kernel(const int* __restrict__ ei,
                                                   int* __restrict__ cursor,
                                                   int* __restrict__ col) {
  int e = blockIdx.x * 256 + threadIdx.x;
  if (e >= N_EDGES) return;
  int srcv = ei[e];
  int dstv = ei[N_EDGES + e];
  srcv = min(max(srcv, 0), N_NODES - 1);
  dstv = min(max(dstv, 0), N_NODES - 1);
  int p = atomicAdd(&cursor[dstv], 1);
  col[p] = srcv;
}

// ---------------- GEMM1: h1p = bf16( dinv .* (X @ W1) )  [50000x128 @ 128x128] -------
// 128x128 tile/block, BK=64 two-stage K loop -> 64 KiB LDS -> 2 blocks/CU.
// Epilogue stores bf16 (halves agg1's gather bytes + write volume).
__global__ __launch_bounds__(256) void gemm1_kernel(const float* __restrict__ X,
                                                    const float* __restrict__ W,
                                                    const float* __restrict__ dinv,
                                                    __hip_bfloat16* __restrict__ h1p) {
  __shared__ float xs[128 * 64];
  __shared__ float ws[128 * 64];
  int t = threadIdx.x;
  int row0 = blockIdx.x * 128;
  int wv = t >> 6, lane = t & 63;
  int wr = (wv >> 1) << 6, wc = (wv & 1) << 6;
  int tr = lane >> 3, tc = lane & 7;
  float acc[8][8];
#pragma unroll
  for (int i = 0; i < 8; ++i)
#pragma unroll
    for (int m = 0; m < 8; ++m) acc[i][m] = 0.f;

  for (int h = 0; h < 2; ++h) {
    if (h) __syncthreads();
#pragma unroll
    for (int it = 0; it < 8; ++it) {
      int idx = t + it * 256;
      int r = idx >> 4, kq = idx & 15;
      int gr = row0 + r;
      if (gr >= N_NODES) gr = N_NODES - 1;
      float4 v = *(const float4*)(X + (size_t)gr * 128 + h * 64 + kq * 4);
      *(float4*)(xs + r * 64 + ((kq ^ (r & 7)) << 2)) = v;
    }
#pragma unroll
    for (int it = 0; it < 8; ++it) {
      int idx = t + it * 256;
      int k = idx >> 5, jq = idx & 31;
      float4 v = *(const float4*)(W + (size_t)(h * 64 + k) * 128 + jq * 4);
      int kc = k >> 2, kr = k & 3;
      int j0 = jq * 4;
      ws[(j0 + 0) * 64 + (((kc ^ ((j0 + 0) & 7)) << 2) | kr)] = v.x;
      ws[(j0 + 1) * 64 + (((kc ^ ((j0 + 1) & 7)) << 2) | kr)] = v.y;
      ws[(j0 + 2) * 64 + (((kc ^ ((j0 + 2) & 7)) << 2) | kr)] = v.z;
      ws[(j0 + 3) * 64 + (((kc ^ ((j0 + 3) & 7)) << 2) | kr)] = v.w;
    }
    __syncthreads();
    for (int kq = 0; kq < 16; ++kq) {
      float4 xv[8], wvv[8];
#pragma unroll
      for (int i = 0; i < 8; ++i)
        xv[i] = *(const float4*)(xs + (wr + tr + 8 * i) * 64 + ((kq ^ tr) << 2));
#pragma unroll
      for (int m = 0; m < 8; ++m)
        wvv[m] = *(const float4*)(ws + (wc + tc + 8 * m) * 64 + ((kq ^ tc) << 2));
#pragma unroll
      for (int i = 0; i < 8; ++i)
#pragma unroll
        for (int m = 0; m < 8; ++m) {
          acc[i][m] = fmaf(xv[i].x, wvv[m].x, acc[i][m]);
          acc[i][m] = fmaf(xv[i].y, wvv[m].y, acc[i][m]);
          acc[i][m] = fmaf(xv[i].z, wvv[m].z, acc[i][m]);
          acc[i][m] = fmaf(xv[i].w, wvv[m].w, acc[i][m]);
        }
    }
  }
#pragma unroll
  for (int i = 0; i < 8; ++i) {
    int gr = row0 + wr + tr + 8 * i;
    if (gr < N_NODES) {
      float di = dinv[gr];
#pragma unroll
      for (int m = 0; m < 8; ++m)
        h1p[(size_t)gr * 128 + wc + tc + 8 * m] = __float2bfloat16(di * acc[i][m]);
    }
  }
}

// ---------------- layer-1 aggregation: x2 = relu(dinv.*(h1p + gather-sum) + b1) ------
// bf16 rows (256 B) -> quarter-wave per edge: 16 lanes x 16 B, 4 edges in flight,
// 2 independent accumulator chains. Unpack bf16 via bit-shift (VALU was 18% busy).
__global__ __launch_bounds__(256) void agg1_kernel(const __hip_bfloat16* __restrict__ h1p,
                                                   const int* __restrict__ rowptr,
                                                   const int* __restrict__ col,
                                                   const float* __restrict__ dinv,
                                                   const float* __restrict__ b1,
                                                   float* __restrict__ x2) {
  int wid = (blockIdx.x * 256 + threadIdx.x) >> 6;  // one wave per node
  int lane = threadIdx.x & 63;
  if (wid >= N_NODES) return;
  int rs = rowptr[wid], re = rowptr[wid + 1];
  int q = lane >> 4;    // quarter id: which edge of a group of 4
  int fl = lane & 15;   // 16-byte chunk index within a 256 B row
  const uint4* hp = (const uint4*)h1p;  // 16 uint4 per row
  float a0[8], a1[8];
#pragma unroll
  for (int j = 0; j < 8; ++j) { a0[j] = 0.f; a1[j] = 0.f; }

#define ACC_BF16(A, U)                                                        \
  {                                                                           \
    uint4 u_ = (U);                                                           \
    A[0] += __uint_as_float(u_.x << 16);                                      \
    A[1] += __uint_as_float(u_.x & 0xffff0000u);                              \
    A[2] += __uint_as_float(u_.y << 16);                                      \
    A[3] += __uint_as_float(u_.y & 0xffff0000u);                              \
    A[4] += __uint_as_float(u_.z << 16);                                      \
    A[5] += __uint_as_float(u_.z & 0xffff0000u);                              \
    A[6] += __uint_as_float(u_.w << 16);                                      \
    A[7] += __uint_as_float(u_.w & 0xffff0000u);                              \
  }

  if (q == 0) ACC_BF16(a0, hp[(size_t)wid * 16 + fl]);  // self-loop, once

  for (int base = rs; base < re; base += 64) {
    int idx = base + lane;
    int c = (idx < re) ? col[idx] : 0;
    int nb = min(64, re - base);
    int e = 0;
    for (; e + 8 <= nb; e += 8) {  // 8 edges: quarter q takes e+q and e+4+q
      int s0 = __shfl(c, e + q);
      int s1 = __shfl(c, e + 4 + q);
      uint4 u0 = hp[(size_t)s0 * 16 + fl];
      uint4 u1 = hp[(size_t)s1 * 16 + fl];
      ACC_BF16(a0, u0);
      ACC_BF16(a1, u1);
    }
    for (; e < nb; e += 4) {  // tail: quarter q takes e+q if in range
      if (e + q < nb) {
        int s0 = __shfl(c, e + q);
        ACC_BF16(a0, hp[(size_t)s0 * 16 + fl]);
      }
    }
  }
#undef ACC_BF16

#pragma unroll
  for (int j = 0; j < 8; ++j) {
    float v = a0[j] + a1[j];
    v += __shfl_xor(v, 16);  // combine quarters 0<->1, 2<->3
    v += __shfl_xor(v, 32);  // combine halves
    a0[j] = v;
  }
  if (q == 0) {  // lanes 0-15 hold full sums for features [fl*8, fl*8+8)
    float di = dinv[wid];
    float4 bb0 = ((const float4*)b1)[fl * 2];
    float4 bb1 = ((const float4*)b1)[fl * 2 + 1];
    float4 o0, o1;
    o0.x = fmaxf(fmaf(di, a0[0], bb0.x), 0.f);
    o0.y = fmaxf(fmaf(di, a0[1], bb0.y), 0.f);
    o0.z = fmaxf(fmaf(di, a0[2], bb0.z), 0.f);
    o0.w = fmaxf(fmaf(di, a0[3], bb0.w), 0.f);
    o1.x = fmaxf(fmaf(di, a0[4], bb1.x), 0.f);
    o1.y = fmaxf(fmaf(di, a0[5], bb1.y), 0.f);
    o1.z = fmaxf(fmaf(di, a0[6], bb1.z), 0.f);
    o1.w = fmaxf(fmaf(di, a0[7], bb1.w), 0.f);
    *(float4*)(x2 + (size_t)wid * 128 + fl * 8) = o0;
    *(float4*)(x2 + (size_t)wid * 128 + fl * 8 + 4) = o1;
  }
}

// ---------------- GEMM2: h2p = dinv .* (x2 @ W2), rows PADDED to 48 floats ----------
__global__ __launch_bounds__(256) void gemm2_kernel(const float* __restrict__ X2,
                                                    const float* __restrict__ W2,
                                                    const float* __restrict__ dinv,
                                                    float* __restrict__ h2p) {
  __shared__ float xs[64 * 128];
  __shared__ float ws[40 * 128];
  int t = threadIdx.x;
  int row0 = blockIdx.x * 64;
#pragma unroll
  for (int it = 0; it < 8; ++it) {
    int idx = t + it * 256;
    int r = idx >> 5, kq = idx & 31;
    int gr = row0 + r;
    if (gr >= N_NODES) gr = N_NODES - 1;
    float4 v = *(const float4*)(X2 + (size_t)gr * 128 + kq * 4);
    *(float4*)(xs + r * 128 + ((kq ^ (r & 7)) << 2)) = v;
  }
  for (int idx = t; idx < 1280; idx += 256) {  // W2: [128][40] -> ws[j][swz(k)]
    int k = idx / 10, jq = idx % 10;
    float4 v = *(const float4*)(W2 + k * 40 + jq * 4);
    int kc = k >> 2, kr = k & 3;
    int j0 = jq * 4;
    ws[(j0 + 0) * 128 + (((kc ^ ((j0 + 0) & 7)) << 2) | kr)] = v.x;
    ws[(j0 + 1) * 128 + (((kc ^ ((j0 + 1) & 7)) << 2) | kr)] = v.y;
    ws[(j0 + 2) * 128 + (((kc ^ ((j0 + 2) & 7)) << 2) | kr)] = v.z;
    ws[(j0 + 3) * 128 + (((kc ^ ((j0 + 3) & 7)) << 2) | kr)] = v.w;
  }
  __syncthreads();
  int wv = t >> 6, lane = t & 63;
  int tr = lane >> 3, tc = lane & 7;
  int rbase = wv * 16;
  float acc[2][5];
#pragma unroll
  for (int i = 0; i < 2; ++i)
#pragma unroll
    for (int m = 0; m < 5; ++m) acc[i][m] = 0.f;
  for (int kq = 0; kq < 32; ++kq) {
    float4 xv[2], wvv[5];
#pragma unroll
    for (int i = 0; i < 2; ++i)
      xv[i] = *(const float4*)(xs + (rbase + tr + 8 * i) * 128 + ((kq ^ tr) << 2));
#pragma unroll
    for (int m = 0; m < 5; ++m)
      wvv[m] = *(const float4*)(ws + (tc + 8 * m) * 128 + ((kq ^ tc) << 2));
#pragma unroll
    for (int i = 0; i < 2; ++i)
#pragma unroll
      for (int m = 0; m < 5; ++m) {
        acc[i][m] = fmaf(xv[i].x, wvv[m].x, acc[i][m]);
        acc[i][m] = fmaf(xv[i].y, wvv[m].y, acc[i][m]);
        acc[i][m] = fmaf(xv[i].z, wvv[m].z, acc[i][m]);
        acc[i][m] = fmaf(xv[i].w, wvv[m].w, acc[i][m]);
      }
  }
#pragma unroll
  for (int i = 0; i < 2; ++i) {
    int gr = row0 + rbase + tr + 8 * i;
    if (gr < N_NODES) {
      float di = dinv[gr];
#pragma unroll
      for (int m = 0; m < 5; ++m)
        h2p[(size_t)gr * 48 + tc + 8 * m] = di * acc[i][m];  // padded stride
    }
  }
}

// ------- layer-2 aggregation fused with bias + log_softmax, writes d_out -------
__global__ __launch_bounds__(256) void agg2_softmax_kernel(const float* __restrict__ h2p,
                                                           const int* __restrict__ rowptr,
                                                           const int* __restrict__ col,
                                                           const float* __restrict__ dinv,
                                                           const float* __restrict__ b2,
                                                           float* __restrict__ out) {
  int wid = (blockIdx.x * 256 + threadIdx.x) >> 6;  // one wave per node
  int lane = threadIdx.x & 63;
  if (wid >= N_NODES) return;
  int rs = rowptr[wid], re = rowptr[wid + 1];
  bool act = lane < 40;
  float ac0 = act ? h2p[(size_t)wid * 48 + lane] : 0.f;
  float ac1 = 0.f, ac2 = 0.f, ac3 = 0.f;
  for (int base = rs; base < re; base += 64) {
    int idx = base + lane;
    int c = (idx < re) ? col[idx] : 0;
    int nb = min(64, re - base);
    int e = 0;
    for (; e + 4 <= nb; e += 4) {
      int s0 = __shfl(c, e), s1 = __shfl(c, e + 1);
      int s2 = __shfl(c, e + 2), s3 = __shfl(c, e + 3);
      if (act) {
        ac0 += h2p[(size_t)s0 * 48 + lane];
        ac1 += h2p[(size_t)s1 * 48 + lane];
        ac2 += h2p[(size_t)s2 * 48 + lane];
        ac3 += h2p[(size_t)s3 * 48 + lane];
      }
    }
    for (; e < nb; ++e) {
      int s0 = __shfl(c, e);
      if (act) ac0 += h2p[(size_t)s0 * 48 + lane];
    }
  }
  float acc = (ac0 + ac1) + (ac2 + ac3);
  float v = act ? fmaf(dinv[wid], acc, b2[lane]) : -1e30f;
  float m = v;
#pragma unroll
  for (int off = 32; off > 0; off >>= 1) m = fmaxf(m, __shfl_xor(m, off));
  float ex = act ? expf(v - m) : 0.f;
  float ssum = ex;
#pragma unroll
  for (int off = 32; off > 0; off >>= 1) ssum += __shfl_xor(ssum, off);
  float ls = logf(ssum);
  if (act) out[(size_t)wid * 40 + lane] = v - m - ls;
}

extern "C" void kernel_launch(void* const* d_in, const int* in_sizes, int n_in,
                              void* d_out, int out_size, void* d_ws, size_t ws_size,
                              hipStream_t stream) {
  const float* X = (const float*)d_in[0];
  const int* ei = (const int*)d_in[1];  // [2][E] int32 per harness contract
  const float* W1 = (const float*)d_in[2];
  const float* b1 = (const float*)d_in[3];
  const float* W2 = (const float*)d_in[4];
  const float* b2 = (const float*)d_in[5];
  float* out = (float*)d_out;

  char* p = (char*)d_ws;
  auto carve = [&](size_t bytes) -> void* {
    void* q = (void*)p;
    p += (bytes + 255) & ~(size_t)255;
    return q;
  };
  __hip_bfloat16* h1p = (__hip_bfloat16*)carve((size_t)N_NODES * 128 * 2);  // 12.8 MB bf16
  float* x2 = (float*)carve((size_t)N_NODES * 128 * 4);   // 25.6 MB
  float* h2p = (float*)carve((size_t)N_NODES * 48 * 4);   // 9.6 MB (padded rows)
  int* col = (int*)carve((size_t)N_EDGES * 4);            // 3.2 MB
  int* cnt = (int*)carve((size_t)N_NODES * 4);
  int* rowptr = (int*)carve((size_t)(N_NODES + 1) * 4);
  int* cursor = (int*)carve((size_t)N_NODES * 4);
  float* dinv = (float*)carve((size_t)N_NODES * 4);
  int* bsum = (int*)carve((size_t)SCAN_NB * 4);

  hipMemsetAsync(cnt, 0, (size_t)N_NODES * 4, stream);
  count_kernel<<<(N_EDGES + 255) / 256, 256, 0, stream>>>(ei, cnt);
  scan_reduce<<<SCAN_NB, 256, 0, stream>>>(cnt, bsum);
  scan_block<<<1, 128, 0, stream>>>(bsum);
  scan_final<<<SCAN_NB, 256, 0, stream>>>(cnt, bsum, rowptr, cursor, dinv);
  fill_kernel<<<(N_EDGES + 255) / 256, 256, 0, stream>>>(ei, cursor, col);
  gemm1_kernel<<<(N_NODES + 127) / 128, 256, 0, stream>>>(X, W1, dinv, h1p);
  agg1_kernel<<<(N_NODES + 3) / 4, 256, 0, stream>>>(h1p, rowptr, col, dinv, b1, x2);
  gemm2_kernel<<<(N_NODES + 63) / 64, 256, 0, stream>>>(x2, W2, dinv, h2p);
  agg2_softmax_kernel<<<(N_NODES + 3) / 4, 256, 0, stream>>>(h2p, rowptr, col, dinv, b2, out);
}

// Round 14
// 268.843 us; speedup vs baseline: 1.7446x; 1.1017x over previous
//
#include <hip/hip_runtime.h>
#include <hip/hip_bf16.h>
#include <math.h>

#define N_NODES 50000
#define N_EDGES 800000
// F_IN = HIDDEN = 128, N_CLASSES = 40
// h1u: UNSCALED bf16 X@W1 (dinv applied in agg1 -> gemm1 has no dinv dependency
// and can legally overlap the degree histogram). h2p: f32 rows padded to 48.

#define SCAN_CHUNK 512
#define SCAN_NB ((N_NODES + SCAN_CHUNK - 1) / SCAN_CHUNK)  // 98

#define GEMM1_NB ((N_NODES + 127) / 128)   // 391
#define COUNT_NB ((N_EDGES + 255) / 256)   // 3125

// ------- fused: gemm1 (blocks [0,391)) || degree histogram (blocks [391,3516)) -------
// count is atomic-latency-bound, gemm1 is FMA/LDS-bound with ~0 HBM: orthogonal
// resources -> co-resident waves overlap. R13 lesson: gemm1 must NOT read dinv
// (produced later by scan_final) -> store UNSCALED bf16.
__global__ __launch_bounds__(256) void gemm1_count_kernel(
    const float* __restrict__ X, const float* __restrict__ W,
    __hip_bfloat16* __restrict__ h1u,
    const int* __restrict__ ei, int* __restrict__ cnt) {
  __shared__ float xs[128 * 64];
  __shared__ float ws[128 * 64];
  int bid = blockIdx.x;
  int t = threadIdx.x;
  if (bid >= GEMM1_NB) {  // ---- count branch ----
    int e = (bid - GEMM1_NB) * 256 + t;
    if (e < N_EDGES) {
      int d = ei[N_EDGES + e];
      d = min(max(d, 0), N_NODES - 1);  // defensive clamp
      atomicAdd(&cnt[d], 1);
    }
    return;
  }
  // ---- gemm1 branch: 128x128 tile, BK=64 two-stage, 64 KiB LDS, 2 blocks/CU ----
  int row0 = bid * 128;
  int wv = t >> 6, lane = t & 63;
  int wr = (wv >> 1) << 6, wc = (wv & 1) << 6;
  int tr = lane >> 3, tc = lane & 7;
  float acc[8][8];
#pragma unroll
  for (int i = 0; i < 8; ++i)
#pragma unroll
    for (int m = 0; m < 8; ++m) acc[i][m] = 0.f;

  for (int h = 0; h < 2; ++h) {
    if (h) __syncthreads();
#pragma unroll
    for (int it = 0; it < 8; ++it) {
      int idx = t + it * 256;
      int r = idx >> 4, kq = idx & 15;
      int gr = row0 + r;
      if (gr >= N_NODES) gr = N_NODES - 1;
      float4 v = *(const float4*)(X + (size_t)gr * 128 + h * 64 + kq * 4);
      *(float4*)(xs + r * 64 + ((kq ^ (r & 7)) << 2)) = v;
    }
#pragma unroll
    for (int it = 0; it < 8; ++it) {
      int idx = t + it * 256;
      int k = idx >> 5, jq = idx & 31;
      float4 v = *(const float4*)(W + (size_t)(h * 64 + k) * 128 + jq * 4);
      int kc = k >> 2, kr = k & 3;
      int j0 = jq * 4;
      ws[(j0 + 0) * 64 + (((kc ^ ((j0 + 0) & 7)) << 2) | kr)] = v.x;
      ws[(j0 + 1) * 64 + (((kc ^ ((j0 + 1) & 7)) << 2) | kr)] = v.y;
      ws[(j0 + 2) * 64 + (((kc ^ ((j0 + 2) & 7)) << 2) | kr)] = v.z;
      ws[(j0 + 3) * 64 + (((kc ^ ((j0 + 3) & 7)) << 2) | kr)] = v.w;
    }
    __syncthreads();
    for (int kq = 0; kq < 16; ++kq) {
      float4 xv[8], wvv[8];
#pragma unroll
      for (int i = 0; i < 8; ++i)
        xv[i] = *(const float4*)(xs + (wr + tr + 8 * i) * 64 + ((kq ^ tr) << 2));
#pragma unroll
      for (int m = 0; m < 8; ++m)
        wvv[m] = *(const float4*)(ws + (wc + tc + 8 * m) * 64 + ((kq ^ tc) << 2));
#pragma unroll
      for (int i = 0; i < 8; ++i)
#pragma unroll
        for (int m = 0; m < 8; ++m) {
          acc[i][m] = fmaf(xv[i].x, wvv[m].x, acc[i][m]);
          acc[i][m] = fmaf(xv[i].y, wvv[m].y, acc[i][m]);
          acc[i][m] = fmaf(xv[i].z, wvv[m].z, acc[i][m]);
          acc[i][m] = fmaf(xv[i].w, wvv[m].w, acc[i][m]);
        }
    }
  }
#pragma unroll
  for (int i = 0; i < 8; ++i) {
    int gr = row0 + wr + tr + 8 * i;
    if (gr < N_NODES) {
#pragma unroll
      for (int m = 0; m < 8; ++m)
        h1u[(size_t)gr * 128 + wc + tc + 8 * m] = __float2bfloat16(acc[i][m]);
    }
  }
}

// ---------------- 3-pass exclusive scan (R8 known-good; coop/single-block fusions
// both regressed: 256-block coop grid = 220us, 1-block scan = 148us. occupancy!) ----
__global__ __launch_bounds__(256) void scan_reduce(const int* __restrict__ cnt,
                                                   int* __restrict__ bsum) {
  __shared__ int s[256];
  int t = threadIdx.x;
  int i0 = blockIdx.x * SCAN_CHUNK + t * 2;
  int v = 0;
  if (i0 < N_NODES) v += cnt[i0];
  if (i0 + 1 < N_NODES) v += cnt[i0 + 1];
  s[t] = v;
  __syncthreads();
  for (int off = 128; off > 0; off >>= 1) {
    if (t < off) s[t] += s[t + off];
    __syncthreads();
  }
  if (t == 0) bsum[blockIdx.x] = s[0];
}

__global__ void scan_block(int* bsum) {
  __shared__ int s[128];
  int t = threadIdx.x;
  int v = (t < SCAN_NB) ? bsum[t] : 0;
  s[t] = v;
  __syncthreads();
  for (int off = 1; off < 128; off <<= 1) {
    int a = (t >= off) ? s[t - off] : 0;
    __syncthreads();
    s[t] += a;
    __syncthreads();
  }
  if (t < SCAN_NB) bsum[t] = s[t] - v;  // exclusive
}

__global__ __launch_bounds__(256) void scan_final(const int* __restrict__ cnt,
                                                  const int* __restrict__ bsum,
                                                  int* __restrict__ rowptr,
                                                  int* __restrict__ cursor,
                                                  float* __restrict__ dinv) {
  __shared__ int s[256];
  int t = threadIdx.x;
  int b = blockIdx.x;
  int i0 = b * SCAN_CHUNK + t * 2;
  int c0 = (i0 < N_NODES) ? cnt[i0] : 0;
  int c1 = (i0 + 1 < N_NODES) ? cnt[i0 + 1] : 0;
  int v = c0 + c1;
  s[t] = v;
  __syncthreads();
  for (int off = 1; off < 256; off <<= 1) {
    int a = (t >= off) ? s[t - off] : 0;
    __syncthreads();
    s[t] += a;
    __syncthreads();
  }
  int excl = s[t] - v + bsum[b];
  if (i0 < N_NODES) {
    rowptr[i0] = excl;
    cursor[i0] = excl;
    dinv[i0] = rsqrtf((float)(c0 + 1));  // deg includes self-loop, > 0
  }
  if (i0 + 1 < N_NODES) {
    rowptr[i0 + 1] = excl + c0;
    cursor[i0 + 1] = excl + c0;
    dinv[i0 + 1] = rsqrtf((float)(c1 + 1));
  }
  if (b == 0 && t == 0) rowptr[N_NODES] = N_EDGES;
}

__global__ __launch_bounds__(256) void fill_kernel(const int* __restrict__ ei,
                                                   int* __restrict__ cursor,
                                                   int* __restrict__ col) {
  int e = blockIdx.x * 256 + threadIdx.x;
  if (e >= N_EDGES) return;
  int srcv = ei[e];
  int dstv = ei[N_EDGES + e];
  srcv = min(max(srcv, 0), N_NODES - 1);
  dstv = min(max(dstv, 0), N_NODES - 1);
  int p = atomicAdd(&cursor[dstv], 1);
  col[p] = srcv;
}

// -------- layer-1 aggregation: x2 = relu(dinv_i*(Σ dinv_s*h1u_s) + b1) --------------
// h1u is UNSCALED; dinv_s applied at gather time (per-edge dinv[col] gather, 4B,
// L2-resident) via weighted FMA accumulation. Quarter-wave per edge, bf16 rows.
__global__ __launch_bounds__(256) void agg1_kernel(const __hip_bfloat16* __restrict__ h1u,
                                                   const int* __restrict__ rowptr,
                                                   const int* __restrict__ col,
                                                   const float* __restrict__ dinv,
                                                   const float* __restrict__ b1,
                                                   float* __restrict__ x2) {
  int wid = (blockIdx.x * 256 + threadIdx.x) >> 6;  // one wave per node
  int lane = threadIdx.x & 63;
  if (wid >= N_NODES) return;
  int rs = rowptr[wid], re = rowptr[wid + 1];
  int q = lane >> 4;    // quarter id: which edge of a group of 4
  int fl = lane & 15;   // 16-byte chunk index within a 256 B row
  const uint4* hp = (const uint4*)h1u;  // 16 uint4 per row
  float diw = dinv[wid];
  float a0[8], a1[8];
#pragma unroll
  for (int j = 0; j < 8; ++j) { a0[j] = 0.f; a1[j] = 0.f; }

#define ACC_BF16_W(A, U, Wt)                                                  \
  {                                                                           \
    uint4 u_ = (U);                                                           \
    float w_ = (Wt);                                                          \
    A[0] = fmaf(w_, __uint_as_float(u_.x << 16), A[0]);                       \
    A[1] = fmaf(w_, __uint_as_float(u_.x & 0xffff0000u), A[1]);               \
    A[2] = fmaf(w_, __uint_as_float(u_.y << 16), A[2]);                       \
    A[3] = fmaf(w_, __uint_as_float(u_.y & 0xffff0000u), A[3]);               \
    A[4] = fmaf(w_, __uint_as_float(u_.z << 16), A[4]);                       \
    A[5] = fmaf(w_, __uint_as_float(u_.z & 0xffff0000u), A[5]);               \
    A[6] = fmaf(w_, __uint_as_float(u_.w << 16), A[6]);                       \
    A[7] = fmaf(w_, __uint_as_float(u_.w & 0xffff0000u), A[7]);               \
  }

  if (q == 0) ACC_BF16_W(a0, hp[(size_t)wid * 16 + fl], diw);  // self-loop, once

  for (int base = rs; base < re; base += 64) {
    int idx = base + lane;
    int c = (idx < re) ? col[idx] : 0;
    float dv = (idx < re) ? dinv[c] : 0.f;
    int nb = min(64, re - base);
    int e = 0;
    for (; e + 8 <= nb; e += 8) {  // 8 edges: quarter q takes e+q and e+4+q
      int s0 = __shfl(c, e + q);
      int s1 = __shfl(c, e + 4 + q);
      float d0 = __shfl(dv, e + q);
      float d1 = __shfl(dv, e + 4 + q);
      uint4 u0 = hp[(size_t)s0 * 16 + fl];
      uint4 u1 = hp[(size_t)s1 * 16 + fl];
      ACC_BF16_W(a0, u0, d0);
      ACC_BF16_W(a1, u1, d1);
    }
    for (; e < nb; e += 4) {  // tail: quarter q takes e+q if in range
      if (e + q < nb) {
        int s0 = __shfl(c, e + q);
        float d0 = __shfl(dv, e + q);
        ACC_BF16_W(a0, hp[(size_t)s0 * 16 + fl], d0);
      }
    }
  }
#undef ACC_BF16_W

#pragma unroll
  for (int j = 0; j < 8; ++j) {
    float v = a0[j] + a1[j];
    v += __shfl_xor(v, 16);  // combine quarters 0<->1, 2<->3
    v += __shfl_xor(v, 32);  // combine halves
    a0[j] = v;
  }
  if (q == 0) {  // lanes 0-15 hold full sums for features [fl*8, fl*8+8)
    float4 bb0 = ((const float4*)b1)[fl * 2];
    float4 bb1 = ((const float4*)b1)[fl * 2 + 1];
    float4 o0, o1;
    o0.x = fmaxf(fmaf(diw, a0[0], bb0.x), 0.f);
    o0.y = fmaxf(fmaf(diw, a0[1], bb0.y), 0.f);
    o0.z = fmaxf(fmaf(diw, a0[2], bb0.z), 0.f);
    o0.w = fmaxf(fmaf(diw, a0[3], bb0.w), 0.f);
    o1.x = fmaxf(fmaf(diw, a0[4], bb1.x), 0.f);
    o1.y = fmaxf(fmaf(diw, a0[5], bb1.y), 0.f);
    o1.z = fmaxf(fmaf(diw, a0[6], bb1.z), 0.f);
    o1.w = fmaxf(fmaf(diw, a0[7], bb1.w), 0.f);
    *(float4*)(x2 + (size_t)wid * 128 + fl * 8) = o0;
    *(float4*)(x2 + (size_t)wid * 128 + fl * 8 + 4) = o1;
  }
}

// ---------------- GEMM2: h2p = dinv .* (x2 @ W2), rows PADDED to 48 floats ----------
__global__ __launch_bounds__(256) void gemm2_kernel(const float* __restrict__ X2,
                                                    const float* __restrict__ W2,
                                                    const float* __restrict__ dinv,
                                                    float* __restrict__ h2p) {
  __shared__ float xs[64 * 128];
  __shared__ float ws[40 * 128];
  int t = threadIdx.x;
  int row0 = blockIdx.x * 64;
#pragma unroll
  for (int it = 0; it < 8; ++it) {
    int idx = t + it * 256;
    int r = idx >> 5, kq = idx & 31;
    int gr = row0 + r;
    if (gr >= N_NODES) gr = N_NODES - 1;
    float4 v = *(const float4*)(X2 + (size_t)gr * 128 + kq * 4);
    *(float4*)(xs + r * 128 + ((kq ^ (r & 7)) << 2)) = v;
  }
  for (int idx = t; idx < 1280; idx += 256) {  // W2: [128][40] -> ws[j][swz(k)]
    int k = idx / 10, jq = idx % 10;
    float4 v = *(const float4*)(W2 + k * 40 + jq * 4);
    int kc = k >> 2, kr = k & 3;
    int j0 = jq * 4;
    ws[(j0 + 0) * 128 + (((kc ^ ((j0 + 0) & 7)) << 2) | kr)] = v.x;
    ws[(j0 + 1) * 128 + (((kc ^ ((j0 + 1) & 7)) << 2) | kr)] = v.y;
    ws[(j0 + 2) * 128 + (((kc ^ ((j0 + 2) & 7)) << 2) | kr)] = v.z;
    ws[(j0 + 3) * 128 + (((kc ^ ((j0 + 3) & 7)) << 2) | kr)] = v.w;
  }
  __syncthreads();
  int wv = t >> 6, lane = t & 63;
  int tr = lane >> 3, tc = lane & 7;
  int rbase = wv * 16;
  float acc[2][5];
#pragma unroll
  for (int i = 0; i < 2; ++i)
#pragma unroll
    for (int m = 0; m < 5; ++m) acc[i][m] = 0.f;
  for (int kq = 0; kq < 32; ++kq) {
    float4 xv[2], wvv[5];
#pragma unroll
    for (int i = 0; i < 2; ++i)
      xv[i] = *(const float4*)(xs + (rbase + tr + 8 * i) * 128 + ((kq ^ tr) << 2));
#pragma unroll
    for (int m = 0; m < 5; ++m)
      wvv[m] = *(const float4*)(ws + (tc + 8 * m) * 128 + ((kq ^ tc) << 2));
#pragma unroll
    for (int i = 0; i < 2; ++i)
#pragma unroll
      for (int m = 0; m < 5; ++m) {
        acc[i][m] = fmaf(xv[i].x, wvv[m].x, acc[i][m]);
        acc[i][m] = fmaf(xv[i].y, wvv[m].y, acc[i][m]);
        acc[i][m] = fmaf(xv[i].z, wvv[m].z, acc[i][m]);
        acc[i][m] = fmaf(xv[i].w, wvv[m].w, acc[i][m]);
      }
  }
#pragma unroll
  for (int i = 0; i < 2; ++i) {
    int gr = row0 + rbase + tr + 8 * i;
    if (gr < N_NODES) {
      float di = dinv[gr];
#pragma unroll
      for (int m = 0; m < 5; ++m)
        h2p[(size_t)gr * 48 + tc + 8 * m] = di * acc[i][m];  // padded stride
    }
  }
}

// ------- layer-2 aggregation fused with bias + log_softmax, writes d_out -------
__global__ __launch_bounds__(256) void agg2_softmax_kernel(const float* __restrict__ h2p,
                                                           const int* __restrict__ rowptr,
                                                           const int* __restrict__ col,
                                                           const float* __restrict__ dinv,
                                                           const float* __restrict__ b2,
                                                           float* __restrict__ out) {
  int wid = (blockIdx.x * 256 + threadIdx.x) >> 6;  // one wave per node
  int lane = threadIdx.x & 63;
  if (wid >= N_NODES) return;
  int rs = rowptr[wid], re = rowptr[wid + 1];
  bool act = lane < 40;
  float ac0 = act ? h2p[(size_t)wid * 48 + lane] : 0.f;
  float ac1 = 0.f, ac2 = 0.f, ac3 = 0.f;
  for (int base = rs; base < re; base += 64) {
    int idx = base + lane;
    int c = (idx < re) ? col[idx] : 0;
    int nb = min(64, re - base);
    int e = 0;
    for (; e + 4 <= nb; e += 4) {
      int s0 = __shfl(c, e), s1 = __shfl(c, e + 1);
      int s2 = __shfl(c, e + 2), s3 = __shfl(c, e + 3);
      if (act) {
        ac0 += h2p[(size_t)s0 * 48 + lane];
        ac1 += h2p[(size_t)s1 * 48 + lane];
        ac2 += h2p[(size_t)s2 * 48 + lane];
        ac3 += h2p[(size_t)s3 * 48 + lane];
      }
    }
    for (; e < nb; ++e) {
      int s0 = __shfl(c, e);
      if (act) ac0 += h2p[(size_t)s0 * 48 + lane];
    }
  }
  float acc = (ac0 + ac1) + (ac2 + ac3);
  float v = act ? fmaf(dinv[wid], acc, b2[lane]) : -1e30f;
  float m = v;
#pragma unroll
  for (int off = 32; off > 0; off >>= 1) m = fmaxf(m, __shfl_xor(m, off));
  float ex = act ? expf(v - m) : 0.f;
  float ssum = ex;
#pragma unroll
  for (int off = 32; off > 0; off >>= 1) ssum += __shfl_xor(ssum, off);
  float ls = logf(ssum);
  if (act) out[(size_t)wid * 40 + lane] = v - m - ls;
}

extern "C" void kernel_launch(void* const* d_in, const int* in_sizes, int n_in,
                              void* d_out, int out_size, void* d_ws, size_t ws_size,
                              hipStream_t stream) {
  const float* X = (const float*)d_in[0];
  const int* ei = (const int*)d_in[1];  // [2][E] int32 per harness contract
  const float* W1 = (const float*)d_in[2];
  const float* b1 = (const float*)d_in[3];
  const float* W2 = (const float*)d_in[4];
  const float* b2 = (const float*)d_in[5];
  float* out = (float*)d_out;

  char* p = (char*)d_ws;
  auto carve = [&](size_t bytes) -> void* {
    void* q = (void*)p;
    p += (bytes + 255) & ~(size_t)255;
    return q;
  };
  __hip_bfloat16* h1u = (__hip_bfloat16*)carve((size_t)N_NODES * 128 * 2);  // 12.8 MB bf16
  float* x2 = (float*)carve((size_t)N_NODES * 128 * 4);   // 25.6 MB
  float* h2p = (float*)carve((size_t)N_NODES * 48 * 4);   // 9.6 MB (padded rows)
  int* col = (int*)carve((size_t)N_EDGES * 4);            // 3.2 MB
  int* cnt = (int*)carve((size_t)N_NODES * 4);
  int* rowptr = (int*)carve((size_t)(N_NODES + 1) * 4);
  int* cursor = (int*)carve((size_t)N_NODES * 4);
  float* dinv = (float*)carve((size_t)N_NODES * 4);
  int* bsum = (int*)carve((size_t)SCAN_NB * 4);

  hipMemsetAsync(cnt, 0, (size_t)N_NODES * 4, stream);
  gemm1_count_kernel<<<GEMM1_NB + COUNT_NB, 256, 0, stream>>>(X, W1, h1u, ei, cnt);
  scan_reduce<<<SCAN_NB, 256, 0, stream>>>(cnt, bsum);
  scan_block<<<1, 128, 0, stream>>>(bsum);
  scan_final<<<SCAN_NB, 256, 0, stream>>>(cnt, bsum, rowptr, cursor, dinv);
  fill_kernel<<<(N_EDGES + 255) / 256, 256, 0, stream>>>(ei, cursor, col);
  agg1_kernel<<<(N_NODES + 3) / 4, 256, 0, stream>>>(h1u, rowptr, col, dinv, b1, x2);
  gemm2_kernel<<<(N_NODES + 63) / 64, 256, 0, stream>>>(x2, W2, dinv, h2p);
  agg2_softmax_kernel<<<(N_NODES + 3) / 4, 256, 0, stream>>>(h2p, rowptr, col, dinv, b2, out);
}